// Round 4
// baseline (29.026 us; speedup 1.0000x reference)
//
#include <hip/hip_runtime.h>
#include <hip/hip_bf16.h>

// Chamfer-style loss between two 2-D point clouds (N=M=8192).
// total = sum_n min_m ||p_n - t_m|| + sum_m min_n ||p_n - t_m||, out = total / M.
//
// R4: single fused kernel.
//  - 512-thread blocks (8 waves), ROWS=8 query pts/wave -> 64 q-pts/block,
//    256 blocks total (both directions), 64 KB LDS stage of opposite cloud.
//  - inner loop: ds_read_b128 (2 points/read), 3 VALU ops per pair
//    (h = fma(-2px, tx, fma(-2py, ty, tt)); min).
//  - final reduce fused via last-block pattern (deterministic fixed-order sum).
//    counter zeroed per call by a 4-byte hipMemsetAsync node.

#define ROWS 8
#define WAVES_PER_BLOCK 8
#define THREADS (WAVES_PER_BLOCK * 64)
#define PTS_PER_BLOCK (ROWS * WAVES_PER_BLOCK)   // 64 query points per block
#define MAXB 8192                                 // max opposite-cloud points staged

__global__ __launch_bounds__(THREADS) void chamfer_fused_kernel(
    const float2* __restrict__ P, int N,
    const float2* __restrict__ T, int M,
    int blocksP,
    float* __restrict__ block_sums,
    unsigned int* __restrict__ counter,
    float inv_M,
    float* __restrict__ out)
{
    __shared__ float2 sB[MAXB];                   // 64 KB
    __shared__ float wsum[WAVES_PER_BLOCK];
    __shared__ bool isLast;

    // Uniform per-block direction select.
    const float2* A; const float2* B; int nA, nB; int bid = blockIdx.x;
    if (bid < blocksP) { A = P; nA = N; B = T; nB = M; }
    else               { A = T; nA = M; B = P; nB = N; bid -= blocksP; }

    const int tid  = threadIdx.x;
    const int lane = tid & 63;
    const int wave = tid >> 6;                 // 0..7
    const int n0   = (bid * WAVES_PER_BLOCK + wave) * ROWS;

    // Stage B into LDS with float4 (2 points per load).
    {
        const float4* B4 = (const float4*)B;
        float4* S4 = (float4*)sB;
        const int nB4 = nB >> 1;
        for (int i = tid; i < nB4; i += THREADS) S4[i] = B4[i];
        if ((nB & 1) && tid == 0) sB[nB - 1] = B[nB - 1];
    }

    // Query-constant registers: -2*px, -2*py, |p|^2.
    float m2px[ROWS], m2py[ROWS], pp[ROWS];
    #pragma unroll
    for (int r = 0; r < ROWS; ++r) {
        float2 p;
        if (n0 + r < nA) p = A[n0 + r];
        else             p = make_float2(0.0f, 0.0f);
        m2px[r] = -2.0f * p.x;
        m2py[r] = -2.0f * p.y;
        pp[r]   = fmaf(p.x, p.x, p.y * p.y);
    }

    float g[ROWS];
    #pragma unroll
    for (int r = 0; r < ROWS; ++r) g[r] = 3.402823466e+38f;

    __syncthreads();

    // Lanes stride the staged cloud, 2 points per ds_read_b128, 3 ops/pair.
    {
        const float4* S4 = (const float4*)sB;
        const int nB4 = nB >> 1;
        #pragma unroll 2
        for (int m = lane; m < nB4; m += 64) {
            float4 tc = S4[m];
            float tt0 = fmaf(tc.x, tc.x, tc.y * tc.y);
            float tt1 = fmaf(tc.z, tc.z, tc.w * tc.w);
            #pragma unroll
            for (int r = 0; r < ROWS; ++r) {
                float h0 = fmaf(m2px[r], tc.x, fmaf(m2py[r], tc.y, tt0));
                float h1 = fmaf(m2px[r], tc.z, fmaf(m2py[r], tc.w, tt1));
                g[r] = fminf(g[r], fminf(h0, h1));
            }
        }
        if (nB & 1) {
            float2 t = sB[nB - 1];
            float tt = fmaf(t.x, t.x, t.y * t.y);
            #pragma unroll
            for (int r = 0; r < ROWS; ++r)
                g[r] = fminf(g[r], fmaf(m2px[r], t.x, fmaf(m2py[r], t.y, tt)));
        }
    }

    // Wave-wide min reduce (64 lanes).
    #pragma unroll
    for (int r = 0; r < ROWS; ++r) {
        float v = g[r];
        #pragma unroll
        for (int off = 32; off >= 1; off >>= 1)
            v = fminf(v, __shfl_xor(v, off, 64));
        g[r] = v;
    }

    // Per-wave sum of sqrt(clamped min d2), then block sum.
    if (lane == 0) {
        float s = 0.0f;
        #pragma unroll
        for (int r = 0; r < ROWS; ++r)
            if (n0 + r < nA) s += sqrtf(fmaxf(pp[r] + g[r], 0.0f));
        wsum[wave] = s;
    }
    __syncthreads();
    if (tid == 0) {
        float s = 0.0f;
        #pragma unroll
        for (int w = 0; w < WAVES_PER_BLOCK; ++w) s += wsum[w];
        block_sums[blockIdx.x] = s;
        __threadfence();
        unsigned int old = atomicAdd(counter, 1u);
        isLast = (old == gridDim.x - 1);
    }
    __syncthreads();

    // Last-finishing block performs the deterministic fixed-order final sum.
    if (isLast) {
        __threadfence();
        float s = 0.0f;
        for (int i = tid; i < (int)gridDim.x; i += THREADS) s += block_sums[i];
        #pragma unroll
        for (int off = 32; off >= 1; off >>= 1) s += __shfl_xor(s, off, 64);
        __shared__ float fsum[WAVES_PER_BLOCK];
        if (lane == 0) fsum[wave] = s;
        __syncthreads();
        if (tid == 0) {
            float tot = 0.0f;
            #pragma unroll
            for (int w = 0; w < WAVES_PER_BLOCK; ++w) tot += fsum[w];
            out[0] = tot * inv_M;
        }
    }
}

extern "C" void kernel_launch(void* const* d_in, const int* in_sizes, int n_in,
                              void* d_out, int out_size, void* d_ws, size_t ws_size,
                              hipStream_t stream) {
    const float2* P = (const float2*)d_in[0];
    const float2* T = (const float2*)d_in[1];
    const int N = in_sizes[0] / 2;
    const int M = in_sizes[1] / 2;

    float* out = (float*)d_out;
    float* block_sums = (float*)d_ws;
    unsigned int* counter = (unsigned int*)((char*)d_ws + 4096);

    const int blocksP = (N + PTS_PER_BLOCK - 1) / PTS_PER_BLOCK;
    const int blocksT = (M + PTS_PER_BLOCK - 1) / PTS_PER_BLOCK;
    const int total_blocks = blocksP + blocksT;

    // Zero the completion counter (graph-capturable async memset).
    hipMemsetAsync(counter, 0, sizeof(unsigned int), stream);

    chamfer_fused_kernel<<<total_blocks, THREADS, 0, stream>>>(
        P, N, T, M, blocksP, block_sums, counter, 1.0f / (float)M, out);
}

// Round 5
// 23.862 us; speedup vs baseline: 1.2164x; 1.2164x over previous
//
#include <hip/hip_runtime.h>
#include <hip/hip_bf16.h>

// Chamfer-style loss between two 2-D point clouds (N=M=8192).
// total = sum_n min_m ||p_n - t_m|| + sum_m min_n ||p_n - t_m||, out = total / M.
//
// R5: single fused kernel, NO memset node.
//  - last-block detection via monotone counter + power-of-2 grid mask:
//    among any GRID consecutive atomicAdd results exactly one has
//    (old & (GRID-1)) == GRID-1, for ANY starting counter value -> no reset
//    needed, works under harness poisoning, final sum is fixed-order.
//  - 512-thread blocks, ROWS=8 q-pts/wave, 64 KB LDS stage of opposite cloud.
//  - inner loop: ds_read_b128 (2 pts/read), v_min3 fusion -> 2.5 VALU ops/pair.

#define ROWS 8
#define WAVES_PER_BLOCK 8
#define THREADS (WAVES_PER_BLOCK * 64)
#define PTS_PER_BLOCK (ROWS * WAVES_PER_BLOCK)   // 64 query points per block
#define MAXB 8192                                 // max opposite-cloud points staged

__global__ __launch_bounds__(THREADS) void chamfer_fused_kernel(
    const float2* __restrict__ P, int N,
    const float2* __restrict__ T, int M,
    int blocksP, int total_blocks,
    float* __restrict__ block_sums,
    unsigned int* __restrict__ counter,
    float inv_M,
    float* __restrict__ out)
{
    __shared__ float2 sB[MAXB];                   // 64 KB
    __shared__ float wsum[WAVES_PER_BLOCK];
    __shared__ bool isLast;

    const int tid  = threadIdx.x;
    const int lane = tid & 63;
    const int wave = tid >> 6;                 // 0..7
    const unsigned int gmask = gridDim.x - 1;  // grid is a power of two

    int bid = blockIdx.x;
    if (bid < total_blocks) {
        // Uniform per-block direction select.
        const float2* A; const float2* B; int nA, nB;
        if (bid < blocksP) { A = P; nA = N; B = T; nB = M; }
        else               { A = T; nA = M; B = P; nB = N; bid -= blocksP; }

        const int n0 = (bid * WAVES_PER_BLOCK + wave) * ROWS;

        // Stage B into LDS with float4 (2 points per load).
        {
            const float4* B4 = (const float4*)B;
            float4* S4 = (float4*)sB;
            const int nB4 = nB >> 1;
            for (int i = tid; i < nB4; i += THREADS) S4[i] = B4[i];
            if ((nB & 1) && tid == 0) sB[nB - 1] = B[nB - 1];
        }

        // Query-constant registers: -2*px, -2*py, |p|^2.
        float m2px[ROWS], m2py[ROWS], pp[ROWS];
        #pragma unroll
        for (int r = 0; r < ROWS; ++r) {
            float2 p;
            if (n0 + r < nA) p = A[n0 + r];
            else             p = make_float2(0.0f, 0.0f);
            m2px[r] = -2.0f * p.x;
            m2py[r] = -2.0f * p.y;
            pp[r]   = fmaf(p.x, p.x, p.y * p.y);
        }

        float g[ROWS];
        #pragma unroll
        for (int r = 0; r < ROWS; ++r) g[r] = 3.402823466e+38f;

        __syncthreads();

        // Lanes stride the staged cloud, 2 points per ds_read_b128,
        // v_min3 fusion -> 2.5 VALU ops per pair.
        {
            const float4* S4 = (const float4*)sB;
            const int nB4 = nB >> 1;
            #pragma unroll 2
            for (int m = lane; m < nB4; m += 64) {
                float4 tc = S4[m];
                float tt0 = fmaf(tc.x, tc.x, tc.y * tc.y);
                float tt1 = fmaf(tc.z, tc.z, tc.w * tc.w);
                #pragma unroll
                for (int r = 0; r < ROWS; ++r) {
                    float h0 = fmaf(m2px[r], tc.x, fmaf(m2py[r], tc.y, tt0));
                    float h1 = fmaf(m2px[r], tc.z, fmaf(m2py[r], tc.w, tt1));
                    g[r] = fminf(fminf(g[r], h0), h1);   // -> v_min3_f32
                }
            }
            if (nB & 1) {
                float2 t = sB[nB - 1];
                float tt = fmaf(t.x, t.x, t.y * t.y);
                #pragma unroll
                for (int r = 0; r < ROWS; ++r)
                    g[r] = fminf(g[r], fmaf(m2px[r], t.x, fmaf(m2py[r], t.y, tt)));
            }
        }

        // Wave-wide min reduce (64 lanes).
        #pragma unroll
        for (int r = 0; r < ROWS; ++r) {
            float v = g[r];
            #pragma unroll
            for (int off = 32; off >= 1; off >>= 1)
                v = fminf(v, __shfl_xor(v, off, 64));
            g[r] = v;
        }

        // Per-wave sum of sqrt(clamped min d2), then block sum.
        if (lane == 0) {
            float s = 0.0f;
            #pragma unroll
            for (int r = 0; r < ROWS; ++r)
                if (n0 + r < nA) s += sqrtf(fmaxf(pp[r] + g[r], 0.0f));
            wsum[wave] = s;
        }
        __syncthreads();
        if (tid == 0) {
            float s = 0.0f;
            #pragma unroll
            for (int w = 0; w < WAVES_PER_BLOCK; ++w) s += wsum[w];
            block_sums[blockIdx.x] = s;
            __threadfence();
            unsigned int old = atomicAdd(counter, 1u);
            isLast = ((old & gmask) == gmask);
        }
    } else {
        // Padding block (power-of-2 grid): contributes zero, still counts.
        if (tid == 0) {
            block_sums[blockIdx.x] = 0.0f;
            __threadfence();
            unsigned int old = atomicAdd(counter, 1u);
            isLast = ((old & gmask) == gmask);
        }
    }
    __syncthreads();

    // Last-arriving block performs the deterministic fixed-order final sum.
    if (isLast) {
        __threadfence();
        float s = 0.0f;
        for (int i = tid; i < (int)gridDim.x; i += THREADS) s += block_sums[i];
        #pragma unroll
        for (int off = 32; off >= 1; off >>= 1) s += __shfl_xor(s, off, 64);
        __shared__ float fsum[WAVES_PER_BLOCK];
        if (lane == 0) fsum[wave] = s;
        __syncthreads();
        if (tid == 0) {
            float tot = 0.0f;
            #pragma unroll
            for (int w = 0; w < WAVES_PER_BLOCK; ++w) tot += fsum[w];
            out[0] = tot * inv_M;
        }
    }
}

extern "C" void kernel_launch(void* const* d_in, const int* in_sizes, int n_in,
                              void* d_out, int out_size, void* d_ws, size_t ws_size,
                              hipStream_t stream) {
    const float2* P = (const float2*)d_in[0];
    const float2* T = (const float2*)d_in[1];
    const int N = in_sizes[0] / 2;
    const int M = in_sizes[1] / 2;

    float* out = (float*)d_out;
    float* block_sums = (float*)d_ws;
    unsigned int* counter = (unsigned int*)((char*)d_ws + 16384);

    const int blocksP = (N + PTS_PER_BLOCK - 1) / PTS_PER_BLOCK;
    const int blocksT = (M + PTS_PER_BLOCK - 1) / PTS_PER_BLOCK;
    const int total_blocks = blocksP + blocksT;

    // Round grid up to a power of two for the mod-mask last-block trick.
    int grid = 1;
    while (grid < total_blocks) grid <<= 1;

    chamfer_fused_kernel<<<grid, THREADS, 0, stream>>>(
        P, N, T, M, blocksP, total_blocks, block_sums, counter,
        1.0f / (float)M, out);
}

// Round 6
// 19.544 us; speedup vs baseline: 1.4851x; 1.2209x over previous
//
#include <hip/hip_runtime.h>
#include <hip/hip_bf16.h>

// Chamfer-style loss between two 2-D point clouds (N=M=8192).
// total = sum_n min_m ||p_n - t_m|| + sum_m min_n ||p_n - t_m||, out = total / M.
//
// R6: single fused kernel, NO memset node, NO __threadfence (no L2 flush).
//  - cross-block handoff entirely via device-scope atomics (coherence point):
//      atomicExch(block_sums[bid], s)      ; coherent write
//      s_waitcnt vmcnt(0)                  ; release: exch complete before...
//      atomicAdd(counter, 1)               ; ...the arrival tick
//    last-arriving block (power-of-2 grid mask, monotone counter, no reset)
//    reads partials with atomicAdd(ptr, 0.0f) (coherent read), sums in fixed
//    order -> bitwise-deterministic.
//  - 512-thread blocks, ROWS=8 q-pts/wave, 64 KB LDS stage of opposite cloud.
//  - inner loop: ds_read_b128 (2 pts/read), v_min3 -> 2.5 VALU ops/pair.

#define ROWS 8
#define WAVES_PER_BLOCK 8
#define THREADS (WAVES_PER_BLOCK * 64)
#define PTS_PER_BLOCK (ROWS * WAVES_PER_BLOCK)   // 64 query points per block
#define MAXB 8192                                 // max opposite-cloud points staged

__global__ __launch_bounds__(THREADS) void chamfer_fused_kernel(
    const float2* __restrict__ P, int N,
    const float2* __restrict__ T, int M,
    int blocksP, int total_blocks,
    float* __restrict__ block_sums,
    unsigned int* __restrict__ counter,
    float inv_M,
    float* __restrict__ out)
{
    __shared__ float2 sB[MAXB];                   // 64 KB
    __shared__ float wsum[WAVES_PER_BLOCK];
    __shared__ bool isLast;

    const int tid  = threadIdx.x;
    const int lane = tid & 63;
    const int wave = tid >> 6;                 // 0..7
    const unsigned int gmask = gridDim.x - 1;  // grid is a power of two

    int bid = blockIdx.x;
    if (bid < total_blocks) {
        // Uniform per-block direction select.
        const float2* A; const float2* B; int nA, nB;
        if (bid < blocksP) { A = P; nA = N; B = T; nB = M; }
        else               { A = T; nA = M; B = P; nB = N; bid -= blocksP; }

        const int n0 = (bid * WAVES_PER_BLOCK + wave) * ROWS;

        // Stage B into LDS with float4 (2 points per load).
        {
            const float4* B4 = (const float4*)B;
            float4* S4 = (float4*)sB;
            const int nB4 = nB >> 1;
            for (int i = tid; i < nB4; i += THREADS) S4[i] = B4[i];
            if ((nB & 1) && tid == 0) sB[nB - 1] = B[nB - 1];
        }

        // Query-constant registers: -2*px, -2*py, |p|^2.
        float m2px[ROWS], m2py[ROWS], pp[ROWS];
        #pragma unroll
        for (int r = 0; r < ROWS; ++r) {
            float2 p;
            if (n0 + r < nA) p = A[n0 + r];
            else             p = make_float2(0.0f, 0.0f);
            m2px[r] = -2.0f * p.x;
            m2py[r] = -2.0f * p.y;
            pp[r]   = fmaf(p.x, p.x, p.y * p.y);
        }

        float g[ROWS];
        #pragma unroll
        for (int r = 0; r < ROWS; ++r) g[r] = 3.402823466e+38f;

        __syncthreads();

        // Lanes stride the staged cloud, 2 points per ds_read_b128,
        // v_min3 fusion -> 2.5 VALU ops per pair.
        {
            const float4* S4 = (const float4*)sB;
            const int nB4 = nB >> 1;
            #pragma unroll 2
            for (int m = lane; m < nB4; m += 64) {
                float4 tc = S4[m];
                float tt0 = fmaf(tc.x, tc.x, tc.y * tc.y);
                float tt1 = fmaf(tc.z, tc.z, tc.w * tc.w);
                #pragma unroll
                for (int r = 0; r < ROWS; ++r) {
                    float h0 = fmaf(m2px[r], tc.x, fmaf(m2py[r], tc.y, tt0));
                    float h1 = fmaf(m2px[r], tc.z, fmaf(m2py[r], tc.w, tt1));
                    g[r] = fminf(fminf(g[r], h0), h1);   // -> v_min3_f32
                }
            }
            if (nB & 1) {
                float2 t = sB[nB - 1];
                float tt = fmaf(t.x, t.x, t.y * t.y);
                #pragma unroll
                for (int r = 0; r < ROWS; ++r)
                    g[r] = fminf(g[r], fmaf(m2px[r], t.x, fmaf(m2py[r], t.y, tt)));
            }
        }

        // Wave-wide min reduce (64 lanes).
        #pragma unroll
        for (int r = 0; r < ROWS; ++r) {
            float v = g[r];
            #pragma unroll
            for (int off = 32; off >= 1; off >>= 1)
                v = fminf(v, __shfl_xor(v, off, 64));
            g[r] = v;
        }

        // Per-wave sum of sqrt(clamped min d2), then block partial.
        if (lane == 0) {
            float s = 0.0f;
            #pragma unroll
            for (int r = 0; r < ROWS; ++r)
                if (n0 + r < nA) s += sqrtf(fmaxf(pp[r] + g[r], 0.0f));
            wsum[wave] = s;
        }
        __syncthreads();
        if (tid == 0) {
            float s = 0.0f;
            #pragma unroll
            for (int w = 0; w < WAVES_PER_BLOCK; ++w) s += wsum[w];
            // Coherent write of the partial (atomic -> coherence point, no fence).
            atomicExch(&block_sums[blockIdx.x], s);
            // Release: wait for the exch ack before ticking the arrival counter.
            asm volatile("s_waitcnt vmcnt(0)" ::: "memory");
            unsigned int old = atomicAdd(counter, 1u);
            isLast = ((old & gmask) == gmask);
        }
    } else {
        // Padding block (power-of-2 grid): contributes zero, still counts.
        if (tid == 0) {
            atomicExch(&block_sums[blockIdx.x], 0.0f);
            asm volatile("s_waitcnt vmcnt(0)" ::: "memory");
            unsigned int old = atomicAdd(counter, 1u);
            isLast = ((old & gmask) == gmask);
        }
    }
    __syncthreads();

    // Last-arriving block: fixed-order final sum via coherent atomic reads.
    if (isLast) {
        float s = 0.0f;
        for (int i = tid; i < (int)gridDim.x; i += THREADS)
            s += atomicAdd(&block_sums[i], 0.0f);   // coherent read
        #pragma unroll
        for (int off = 32; off >= 1; off >>= 1) s += __shfl_xor(s, off, 64);
        __shared__ float fsum[WAVES_PER_BLOCK];
        if (lane == 0) fsum[wave] = s;
        __syncthreads();
        if (tid == 0) {
            float tot = 0.0f;
            #pragma unroll
            for (int w = 0; w < WAVES_PER_BLOCK; ++w) tot += fsum[w];
            out[0] = tot * inv_M;
        }
    }
}

extern "C" void kernel_launch(void* const* d_in, const int* in_sizes, int n_in,
                              void* d_out, int out_size, void* d_ws, size_t ws_size,
                              hipStream_t stream) {
    const float2* P = (const float2*)d_in[0];
    const float2* T = (const float2*)d_in[1];
    const int N = in_sizes[0] / 2;
    const int M = in_sizes[1] / 2;

    float* out = (float*)d_out;
    float* block_sums = (float*)d_ws;
    unsigned int* counter = (unsigned int*)((char*)d_ws + 65536);

    const int blocksP = (N + PTS_PER_BLOCK - 1) / PTS_PER_BLOCK;
    const int blocksT = (M + PTS_PER_BLOCK - 1) / PTS_PER_BLOCK;
    const int total_blocks = blocksP + blocksT;

    // Round grid up to a power of two for the mod-mask last-block trick.
    int grid = 1;
    while (grid < total_blocks) grid <<= 1;

    chamfer_fused_kernel<<<grid, THREADS, 0, stream>>>(
        P, N, T, M, blocksP, total_blocks, block_sums, counter,
        1.0f / (float)M, out);
}

// Round 8
// 18.305 us; speedup vs baseline: 1.5857x; 1.0677x over previous
//
#include <hip/hip_runtime.h>
#include <hip/hip_bf16.h>

// Chamfer-style loss between two 2-D point clouds (N=M=8192).
// total = sum_n min_m ||p_n - t_m|| + sum_m min_n ||p_n - t_m||, out = total / M.
//
// R8: two kernels (provably deterministic — kernel boundary gives device-wide
// visibility; no atomics, no fences, no counter reset problem).
//  - kernel 1: 1024-thread blocks (16 waves -> 4 waves/SIMD), ROWS=4
//    q-pts/wave -> 64 q-pts/block, grid = 256 = CU count. 64 KB LDS stage of
//    the opposite cloud; inner loop ds_read_b128 (2 pts/read) + v_min3,
//    ~2.75 VALU ops/pair. Plain store of each block partial.
//  - kernel 2: one 256-thread block, fixed-order reduce of 256 partials.

#define ROWS 4
#define WAVES_PER_BLOCK 16
#define THREADS (WAVES_PER_BLOCK * 64)            // 1024
#define PTS_PER_BLOCK (ROWS * WAVES_PER_BLOCK)    // 64 query points per block
#define MAXB 8192                                  // max opposite-cloud points staged

__global__ __launch_bounds__(THREADS) void chamfer_min_kernel(
    const float2* __restrict__ P, int N,
    const float2* __restrict__ T, int M,
    int blocksP,
    float* __restrict__ block_sums)
{
    __shared__ float2 sB[MAXB];                   // 64 KB
    __shared__ float wsum[WAVES_PER_BLOCK];

    // Uniform per-block direction select.
    const float2* A; const float2* B; int nA, nB; int bid = blockIdx.x;
    if (bid < blocksP) { A = P; nA = N; B = T; nB = M; }
    else               { A = T; nA = M; B = P; nB = N; bid -= blocksP; }

    const int tid  = threadIdx.x;
    const int lane = tid & 63;
    const int wave = tid >> 6;                 // 0..15
    const int n0   = (bid * WAVES_PER_BLOCK + wave) * ROWS;

    // Stage B into LDS with float4 (2 points per load).
    {
        const float4* B4 = (const float4*)B;
        float4* S4 = (float4*)sB;
        const int nB4 = nB >> 1;
        for (int i = tid; i < nB4; i += THREADS) S4[i] = B4[i];
        if ((nB & 1) && tid == 0) sB[nB - 1] = B[nB - 1];
    }

    // Query-constant registers: -2*px, -2*py, |p|^2.
    float m2px[ROWS], m2py[ROWS], pp[ROWS];
    #pragma unroll
    for (int r = 0; r < ROWS; ++r) {
        float2 p;
        if (n0 + r < nA) p = A[n0 + r];
        else             p = make_float2(0.0f, 0.0f);
        m2px[r] = -2.0f * p.x;
        m2py[r] = -2.0f * p.y;
        pp[r]   = fmaf(p.x, p.x, p.y * p.y);
    }

    float g[ROWS];
    #pragma unroll
    for (int r = 0; r < ROWS; ++r) g[r] = 3.402823466e+38f;

    __syncthreads();

    // Lanes stride the staged cloud, 2 points per ds_read_b128,
    // v_min3 fusion -> ~2.75 VALU ops per pair.
    {
        const float4* S4 = (const float4*)sB;
        const int nB4 = nB >> 1;
        #pragma unroll 4
        for (int m = lane; m < nB4; m += 64) {
            float4 tc = S4[m];
            float tt0 = fmaf(tc.x, tc.x, tc.y * tc.y);
            float tt1 = fmaf(tc.z, tc.z, tc.w * tc.w);
            #pragma unroll
            for (int r = 0; r < ROWS; ++r) {
                float h0 = fmaf(m2px[r], tc.x, fmaf(m2py[r], tc.y, tt0));
                float h1 = fmaf(m2px[r], tc.z, fmaf(m2py[r], tc.w, tt1));
                g[r] = fminf(fminf(g[r], h0), h1);   // -> v_min3_f32
            }
        }
        if (nB & 1) {
            float2 t = sB[nB - 1];
            float tt = fmaf(t.x, t.x, t.y * t.y);
            #pragma unroll
            for (int r = 0; r < ROWS; ++r)
                g[r] = fminf(g[r], fmaf(m2px[r], t.x, fmaf(m2py[r], t.y, tt)));
        }
    }

    // Wave-wide min reduce (64 lanes).
    #pragma unroll
    for (int r = 0; r < ROWS; ++r) {
        float v = g[r];
        #pragma unroll
        for (int off = 32; off >= 1; off >>= 1)
            v = fminf(v, __shfl_xor(v, off, 64));
        g[r] = v;
    }

    // Per-wave sum of sqrt(clamped min d2), then block partial (plain store).
    if (lane == 0) {
        float s = 0.0f;
        #pragma unroll
        for (int r = 0; r < ROWS; ++r)
            if (n0 + r < nA) s += sqrtf(fmaxf(pp[r] + g[r], 0.0f));
        wsum[wave] = s;
    }
    __syncthreads();
    if (tid == 0) {
        float s = 0.0f;
        #pragma unroll
        for (int w = 0; w < WAVES_PER_BLOCK; ++w) s += wsum[w];
        block_sums[blockIdx.x] = s;
    }
}

__global__ __launch_bounds__(256) void final_reduce_kernel(
    const float* __restrict__ sums, int n, float inv_M, float* __restrict__ out)
{
    const int tid = threadIdx.x;
    float s = 0.0f;
    for (int i = tid; i < n; i += 256) s += sums[i];
    #pragma unroll
    for (int off = 32; off >= 1; off >>= 1) s += __shfl_xor(s, off, 64);
    __shared__ float wsum[4];
    if ((tid & 63) == 0) wsum[tid >> 6] = s;
    __syncthreads();
    if (tid == 0) out[0] = (wsum[0] + wsum[1] + wsum[2] + wsum[3]) * inv_M;
}

extern "C" void kernel_launch(void* const* d_in, const int* in_sizes, int n_in,
                              void* d_out, int out_size, void* d_ws, size_t ws_size,
                              hipStream_t stream) {
    const float2* P = (const float2*)d_in[0];
    const float2* T = (const float2*)d_in[1];
    const int N = in_sizes[0] / 2;
    const int M = in_sizes[1] / 2;

    float* out = (float*)d_out;
    float* block_sums = (float*)d_ws;

    const int blocksP = (N + PTS_PER_BLOCK - 1) / PTS_PER_BLOCK;
    const int blocksT = (M + PTS_PER_BLOCK - 1) / PTS_PER_BLOCK;
    const int total_blocks = blocksP + blocksT;   // 256 for N=M=8192

    chamfer_min_kernel<<<total_blocks, THREADS, 0, stream>>>(P, N, T, M, blocksP, block_sums);
    final_reduce_kernel<<<1, 256, 0, stream>>>(block_sums, total_blocks, 1.0f / (float)M, out);
}